// Round 10
// baseline (35.260 us; speedup 1.0000x reference)
//
#include <hip/hip_runtime.h>
#include <hip/hip_bf16.h>

// ResidualRotationWarpLayer: out[b,y,x,c] = bilinear(images[b], H_b warp of (x,y))
// H_b = diag(fx,fy,1) * R(q) * diag(fx,fy,1)^-1
// B=32, H=512, W=512, C=3, fp32.
//
// R9 (resubmit after infra failure): 4 samples/thread — each block does TWO
// output rows (y, y+1) of one image. Doubles load-level ILP and reuses the
// shared input row in L1. Fast rcp + wave-uniform interior path, XCD
// swizzle, LDS-staged NT stores.

#define IMG_H 512
#define IMG_W 512
#define IMG_C 3
#define NB    32

typedef float f32x4  __attribute__((ext_vector_type(4)));
typedef float f32x4u __attribute__((ext_vector_type(4), aligned(4)));
typedef float f32x2u __attribute__((ext_vector_type(2), aligned(4)));

__global__ __launch_bounds__(256) void warp_kernel(
    const float* __restrict__ images,
    const float* __restrict__ focal,
    const float* __restrict__ q,
    float* __restrict__ out)
{
    // --- XCD-aware remap: 8192 blocks = 8 XCDs * 1024; each XCD owns 4 images
    const unsigned bid  = blockIdx.x;
    const unsigned xcd  = bid & 7u;
    const unsigned slot = bid >> 3;
    const unsigned virt = xcd * 1024u + slot;
    const int b = (int)(virt >> 8);            // 256 row-pairs per image
    const int y = (int)((virt & 255u) << 1);   // first of two rows

    const int tid = threadIdx.x;

    __shared__ float sH[9];
    __shared__ float s_out[2][IMG_W * IMG_C];   // 2 rows * 1536 floats = 12 KB

    if (tid == 0) {
        // replicate reference op order for numerics
        float q0 = q[0], q1 = q[1], q2 = q[2], q3 = q[3];
        float s = sqrtf(2.0f / (q0*q0 + q1*q1 + q2*q2 + q3*q3));
        q0 *= s; q1 *= s; q2 *= s; q3 *= s;
        float R00 = 1.0f - q2*q2 - q3*q3;
        float R01 = q1*q2 - q3*q0;
        float R02 = q1*q3 + q2*q0;
        float R10 = q1*q2 + q3*q0;
        float R11 = 1.0f - q1*q1 - q3*q3;
        float R12 = q2*q3 - q1*q0;
        float R20 = q1*q3 - q2*q0;
        float R21 = q2*q3 + q1*q0;
        float R22 = 1.0f - q1*q1 - q2*q2;
        float d0 = focal[b*2 + 0];
        float d1 = focal[b*2 + 1];
        sH[0] = (R00*d0)/d0; sH[1] = (R01*d0)/d1; sH[2] = (R02*d0);
        sH[3] = (R10*d1)/d0; sH[4] = (R11*d1)/d1; sH[5] = (R12*d1);
        sH[6] = R20/d0;      sH[7] = R21/d1;      sH[8] = R22;
    }
    __syncthreads();

    const float h0 = sH[0], h3 = sH[3], h6 = sH[6];

    const float ysA = (float)y - 256.0f;
    const float ysB = ysA + 1.0f;
    // row-constant parts of the projective transform
    const float r1A = sH[1]*ysA + sH[2];
    const float r4A = sH[4]*ysA + sH[5];
    const float r7A = sH[7]*ysA + sH[8];
    const float r1B = sH[1]*ysB + sH[2];
    const float r4B = sH[4]*ysB + sH[5];
    const float r7B = sH[7]*ysB + sH[8];

    const float* __restrict__ img_b = images + (unsigned)b * (IMG_H * IMG_W * IMG_C);

    #define SAMPLE(PX, R1, R4, R7, A0, A1, A2) do {                            \
        const float xs = (float)(PX) - 256.0f;                                 \
        float p0 = fmaf(h0, xs, R1);                                           \
        float p1 = fmaf(h3, xs, R4);                                           \
        float p2 = fmaf(h6, xs, R7);                                           \
        float rp2 = __builtin_amdgcn_rcpf(p2);                                 \
        float xw = fmaf(p0, rp2, 256.0f);                                      \
        float yw = fmaf(p1, rp2, 256.0f);                                      \
        float x0f = floorf(xw), y0f = floorf(yw);                              \
        float wx = xw - x0f,   wy = yw - y0f;                                  \
        int x0 = (int)x0f, y0i = (int)y0f;                                     \
        bool interior = (x0 >= 0) & (y0i >= 0) &                               \
                        (x0 < IMG_W-1) & (y0i < IMG_H-1);                      \
        if (__all(interior)) {                                                 \
            /* fast path: no clamps/masks; 6-float pair load per corner row */ \
            const float* bpA = img_b + ((unsigned)y0i * IMG_W + (unsigned)x0) * 3u; \
            const float* bpB = bpA + IMG_W * 3u;                               \
            f32x4u vA0 = *reinterpret_cast<const f32x4u*>(bpA);                \
            f32x2u vA1 = *reinterpret_cast<const f32x2u*>(bpA + 4);            \
            f32x4u vB0 = *reinterpret_cast<const f32x4u*>(bpB);                \
            f32x2u vB1 = *reinterpret_cast<const f32x2u*>(bpB + 4);            \
            float w00 = (1.0f - wx) * (1.0f - wy);                             \
            float w01 = wx * (1.0f - wy);                                      \
            float w10 = (1.0f - wx) * wy;                                      \
            float w11 = wx * wy;                                               \
            A0 = vA0.x*w00 + vA0.w*w01 + vB0.x*w10 + vB0.w*w11;                \
            A1 = vA0.y*w00 + vA1.x*w01 + vB0.y*w10 + vB1.x*w11;                \
            A2 = vA0.z*w00 + vA1.y*w01 + vB0.z*w10 + vB1.y*w11;                \
        } else {                                                               \
            /* slow path: scalar clamped loads, masked weights */              \
            int x1 = x0 + 1, y1i = y0i + 1;                                    \
            bool vx0 = (x0 >= 0) & (x0 <= IMG_W-1);                            \
            bool vx1 = (x1 >= 0) & (x1 <= IMG_W-1);                            \
            bool vy0 = (y0i >= 0) & (y0i <= IMG_H-1);                          \
            bool vy1 = (y1i >= 0) & (y1i <= IMG_H-1);                          \
            unsigned xc0 = (unsigned)min(max(x0, 0), IMG_W-1);                 \
            unsigned xc1 = (unsigned)min(max(x1, 0), IMG_W-1);                 \
            unsigned yc0 = (unsigned)min(max(y0i, 0), IMG_H-1);                \
            unsigned yc1 = (unsigned)min(max(y1i, 0), IMG_H-1);                \
            const float* p00 = img_b + (yc0 * IMG_W + xc0) * IMG_C;            \
            const float* p01 = img_b + (yc0 * IMG_W + xc1) * IMG_C;            \
            const float* p10 = img_b + (yc1 * IMG_W + xc0) * IMG_C;            \
            const float* p11 = img_b + (yc1 * IMG_W + xc1) * IMG_C;            \
            float a00 = p00[0], a01 = p00[1], a02 = p00[2];                    \
            float b00 = p01[0], b01 = p01[1], b02 = p01[2];                    \
            float c00 = p10[0], c01 = p10[1], c02 = p10[2];                    \
            float d00 = p11[0], d01 = p11[1], d02 = p11[2];                    \
            float w00 = (vx0 & vy0) ? (1.0f - wx) * (1.0f - wy) : 0.0f;        \
            float w01 = (vx1 & vy0) ? wx * (1.0f - wy)          : 0.0f;        \
            float w10 = (vx0 & vy1) ? (1.0f - wx) * wy          : 0.0f;        \
            float w11 = (vx1 & vy1) ? wx * wy                   : 0.0f;        \
            A0 = a00*w00 + b00*w01 + c00*w10 + d00*w11;                        \
            A1 = a01*w00 + b01*w01 + c01*w10 + d01*w11;                        \
            A2 = a02*w00 + b02*w01 + c02*w10 + d02*w11;                        \
        }                                                                      \
    } while (0)

    float oA0a, oA1a, oA2a, oA0b, oA1b, oA2b;
    float oB0a, oB1a, oB2a, oB0b, oB1b, oB2b;
    SAMPLE(tid,       r1A, r4A, r7A, oA0a, oA1a, oA2a);
    SAMPLE(tid + 256, r1A, r4A, r7A, oA0b, oA1b, oA2b);
    SAMPLE(tid,       r1B, r4B, r7B, oB0a, oB1a, oB2a);
    SAMPLE(tid + 256, r1B, r4B, r7B, oB0b, oB1b, oB2b);
    #undef SAMPLE

    // stage through LDS for coalesced, vectorized stores
    s_out[0][tid*3 + 0] = oA0a;
    s_out[0][tid*3 + 1] = oA1a;
    s_out[0][tid*3 + 2] = oA2a;
    s_out[0][(tid + 256)*3 + 0] = oA0b;
    s_out[0][(tid + 256)*3 + 1] = oA1b;
    s_out[0][(tid + 256)*3 + 2] = oA2b;
    s_out[1][tid*3 + 0] = oB0a;
    s_out[1][tid*3 + 1] = oB1a;
    s_out[1][tid*3 + 2] = oB2a;
    s_out[1][(tid + 256)*3 + 0] = oB0b;
    s_out[1][(tid + 256)*3 + 1] = oB1b;
    s_out[1][(tid + 256)*3 + 2] = oB2b;
    __syncthreads();

    // per row: 512 px * 3 ch = 1536 floats = 384 float4
    f32x4* outA = reinterpret_cast<f32x4*>(
        out + ((unsigned)(b * IMG_H + y)) * (IMG_W * IMG_C));
    f32x4* outB = outA + 384;
    f32x4 v0 = *reinterpret_cast<const f32x4*>(&s_out[0][tid * 4]);
    __builtin_nontemporal_store(v0, &outA[tid]);
    f32x4 v2 = *reinterpret_cast<const f32x4*>(&s_out[1][tid * 4]);
    __builtin_nontemporal_store(v2, &outB[tid]);
    if (tid < 128) {
        f32x4 v1 = *reinterpret_cast<const f32x4*>(&s_out[0][(256 + tid) * 4]);
        __builtin_nontemporal_store(v1, &outA[256 + tid]);
        f32x4 v3 = *reinterpret_cast<const f32x4*>(&s_out[1][(256 + tid) * 4]);
        __builtin_nontemporal_store(v3, &outB[256 + tid]);
    }
}

extern "C" void kernel_launch(void* const* d_in, const int* in_sizes, int n_in,
                              void* d_out, int out_size, void* d_ws, size_t ws_size,
                              hipStream_t stream) {
    const float* images = (const float*)d_in[0];
    const float* focal  = (const float*)d_in[1];
    const float* q      = (const float*)d_in[2];
    float* out = (float*)d_out;

    dim3 grid(8192);   // (H/2) * B = 256 * 32 row-pairs
    dim3 block(256);
    warp_kernel<<<grid, block, 0, stream>>>(images, focal, q, out);
}